// Round 8
// baseline (413.744 us; speedup 1.0000x reference)
//
#include <hip/hip_runtime.h>
#include <hip/hip_bf16.h>

#define NUM_EXPERTS 8
#define MODEL_DIM 1024
#define INTER_DIM 4096
#define BM 256
#define BN 256
#define BK 64
// A stored as [128][64] half-tiles (8192 elems, 16 KB); B as [256][64] tiles (16384 elems, 32 KB)

typedef __attribute__((ext_vector_type(8))) short short8;
typedef __attribute__((ext_vector_type(8))) unsigned short ushort8;
typedef __attribute__((ext_vector_type(4))) unsigned short ushort4v;
typedef __attribute__((ext_vector_type(4))) float floatx4;

__device__ __forceinline__ unsigned short f2b(float f) {
  union { float f; unsigned int u; } v; v.f = f;
  unsigned int r = v.u + 0x7fffu + ((v.u >> 16) & 1u);
  return (unsigned short)(r >> 16);
}

// async 16B/lane global->LDS (DMA). LDS dest: wave-uniform base + lane*16B.
#define GLOAD16(g, l)                                                                   \
  __builtin_amdgcn_global_load_lds((const __attribute__((address_space(1))) unsigned int*)(g), \
                                   (__attribute__((address_space(3))) unsigned int*)(l), 16, 0, 0)

// ---------------- router: top-2 expert ids per token ----------------
__global__ __launch_bounds__(64) void router_kernel(const float* __restrict__ x,
                                                    const float* __restrict__ gw,
                                                    int* __restrict__ eids, int T) {
  int t = blockIdx.x;
  int lane = threadIdx.x;
  float acc[NUM_EXPERTS];
#pragma unroll
  for (int e = 0; e < NUM_EXPERTS; ++e) acc[e] = 0.f;
  const float* xr = x + (size_t)t * MODEL_DIM;
#pragma unroll 4
  for (int i = lane; i < MODEL_DIM; i += 64) {
    float xv = xr[i];
#pragma unroll
    for (int e = 0; e < NUM_EXPERTS; ++e) acc[e] += xv * gw[e * MODEL_DIM + i];
  }
#pragma unroll
  for (int e = 0; e < NUM_EXPERTS; ++e) {
    float v = acc[e];
#pragma unroll
    for (int off = 32; off > 0; off >>= 1) v += __shfl_xor(v, off);
    acc[e] = v;
  }
  if (lane == 0) {
    int e0 = 0; float b0 = acc[0];
#pragma unroll
    for (int e = 1; e < NUM_EXPERTS; ++e) if (acc[e] > b0) { b0 = acc[e]; e0 = e; }
    int e1 = -1; float b1 = -3.4e38f;
#pragma unroll
    for (int e = 0; e < NUM_EXPERTS; ++e) if (e != e0 && acc[e] > b1) { b1 = acc[e]; e1 = e; }
    eids[t] = e0;
    eids[T + t] = e1;
  }
}

__global__ void hist_kernel(const int* __restrict__ eids, int* __restrict__ counts, int total) {
  int i = blockIdx.x * blockDim.x + threadIdx.x;
  if (i < total) atomicAdd(&counts[eids[i]], 1);
}

// exclusive prefix + 128-aligned padded prefix
__global__ void offsets_kernel(const int* __restrict__ counts, int* __restrict__ offsets,
                               int* __restrict__ cursor, int* __restrict__ poff) {
  if (threadIdx.x == 0 && blockIdx.x == 0) {
    int s = 0, ps = 0;
    for (int e = 0; e < NUM_EXPERTS; ++e) {
      offsets[e] = s; cursor[e] = s; poff[e] = ps;
      s += counts[e];
      ps += ((counts[e] + 127) >> 7) << 7;
    }
    offsets[NUM_EXPERTS] = s;
    poff[NUM_EXPERTS] = ps;
  }
}

__global__ void scatter_kernel(const int* __restrict__ eids, int* __restrict__ cursor,
                               int* __restrict__ token_list, int T) {
  int i = blockIdx.x * blockDim.x + threadIdx.x;
  if (i < 2 * T) {
    int e = eids[i];
    int pos = atomicAdd(&cursor[e], 1);
    int t = (i >= T) ? (i - T) : i;
    token_list[pos] = t;
  }
}

// ---------------- fused gather + fp32->bf16 + half-tile pack of routed A rows ----------
// xg half-tiles: [p/128][kt(16)][128][64]. Zero-fills pad rows.
__global__ __launch_bounds__(256) void gather_tile_kernel(
    const float* __restrict__ X, const int* __restrict__ offsets,
    const int* __restrict__ poff, const int* __restrict__ token_list,
    unsigned short* __restrict__ xg) {
  const int tid = threadIdx.x;
  const int p = blockIdx.x * 8 + (tid >> 5);   // padded row
  const int kb = tid & 31;                     // 32-elem k chunk
  if (p >= poff[NUM_EXPERTS]) return;
  int e = 0;
#pragma unroll
  for (int q = 1; q < NUM_EXPERTS; ++q) if (p >= poff[q]) e = q;
  const int local = p - poff[e];
  const int cnt = offsets[e + 1] - offsets[e];
  unsigned short* dst =
      xg + ((size_t)(p >> 7) * 16 + (kb >> 1)) * 8192 + (p & 127) * 64 + (kb & 1) * 32;
  if (local < cnt) {
    const int tok = token_list[offsets[e] + local];
    const float* src = X + (size_t)tok * MODEL_DIM + kb * 32;
#pragma unroll
    for (int c = 0; c < 4; ++c) {
      float4 v0 = *(const float4*)(src + c * 8);
      float4 v1 = *(const float4*)(src + c * 8 + 4);
      ushort8 s;
      s[0] = f2b(v0.x); s[1] = f2b(v0.y); s[2] = f2b(v0.z); s[3] = f2b(v0.w);
      s[4] = f2b(v1.x); s[5] = f2b(v1.y); s[6] = f2b(v1.z); s[7] = f2b(v1.w);
      *(ushort8*)(dst + c * 8) = s;
    }
  } else {
    const ushort8 z = {0, 0, 0, 0, 0, 0, 0, 0};
#pragma unroll
    for (int c = 0; c < 4; ++c) *(ushort8*)(dst + c * 8) = z;
  }
}

// ---------------- W [E][K][N] fp32 -> [256 n][64 k] bf16 tiles ----------------
// out tiles: [(e*NT + n/256)*KT + k/64][256][64], NT=N/256, KT=K/64
__global__ __launch_bounds__(256) void wconv_kernel(const float* __restrict__ W,
                                                    unsigned short* __restrict__ O,
                                                    int K, int N) {
  __shared__ unsigned short tile[64 * 68];
  const int e = blockIdx.z;
  const int n0 = blockIdx.x * 64;
  const int k0 = blockIdx.y * 64;
  const int NT = N >> 8, KT = K >> 6;
  const float* src = W + (size_t)e * K * N;
  const int tid = threadIdx.x;
  {
    const int kr = tid >> 2;
    const int nq = (tid & 3) * 16;
    const float* p = src + (size_t)(k0 + kr) * N + n0 + nq;
#pragma unroll
    for (int j = 0; j < 4; ++j) {
      float4 v = *(const float4*)(p + j * 4);
      ushort4v s;
      s[0] = f2b(v.x); s[1] = f2b(v.y); s[2] = f2b(v.z); s[3] = f2b(v.w);
      *(ushort4v*)(&tile[kr * 68 + nq + j * 4]) = s;
    }
  }
  __syncthreads();
  {
    const int nl = tid >> 2;            // 0..63 local n
    const int n = n0 + nl;
    const int ks = (tid & 3) * 16;
#pragma unroll
    for (int c = 0; c < 4; ++c) {
      const int tk = k0 + ks + c * 4;
      ushort4v s;
      s[0] = tile[(ks + c * 4 + 0) * 68 + nl];
      s[1] = tile[(ks + c * 4 + 1) * 68 + nl];
      s[2] = tile[(ks + c * 4 + 2) * 68 + nl];
      s[3] = tile[(ks + c * 4 + 3) * 68 + nl];
      unsigned short* q = O + ((size_t)(e * NT + (n >> 8)) * KT + (tk >> 6)) * 16384 +
                          (n & 255) * 64 + (tk & 63);
      *(ushort4v*)q = s;
    }
  }
}

// ---------------- grouped GEMM, 256x256 tile, BK=64, 512 threads, 2-phase ----------
// A from [128][64] half-tiles (stride 8192/step); B from [256][64] tiles (stride 16384/step).
// 8 gload16/thread/step: waves 0-3 stage A half0, 4-7 half1; all waves stage B slice.
#define STAGE(CUR, S) {                                                    \
  _Pragma("unroll")                                                        \
  for (int q = 0; q < 4; ++q)                                              \
    GLOAD16(aSrcW + (size_t)(S) * 8192 + q * 512, &sA[CUR][w * 2048 + q * 512]);  \
  _Pragma("unroll")                                                        \
  for (int q = 0; q < 4; ++q)                                              \
    GLOAD16(bSrcW + (size_t)(S) * 16384 + q * 512, &sB[CUR][w * 2048 + q * 512]); \
}

template <bool UP>
__global__ __launch_bounds__(512) void moe_gemm(
    const unsigned short* __restrict__ A,    // UP: xg half-tiles; DOWN: h half-tiles
    const unsigned short* __restrict__ Bw,   // wT tiles
    unsigned short* __restrict__ Hout,       // UP: h half-tiles out
    float* __restrict__ Out,                 // DOWN: atomic fp32
    const int* __restrict__ offsets,
    const int* __restrict__ poff,
    const int* __restrict__ token_list) {
  constexpr int NSTEP = 16;  // K-chunk 1024 per block (UP full K; DOWN K/4)

  // XCD-chunked decode: expert = b&7
  const int b = blockIdx.x;
  const int e = b & 7;
  const int rem = b >> 3;
  int m_idx, n_idx, ks;
  if constexpr (UP) {
    m_idx = rem & 7;    // m fastest: B-tile reuse on same XCD L2
    n_idx = rem >> 3;   // 0..15
    ks = 0;
  } else {
    n_idx = rem & 3;    // n fastest: A-panel reuse
    m_idx = (rem >> 2) & 7;
    ks = rem >> 5;      // split-K=4
  }

  const int off = offsets[e];
  const int cnt = offsets[e + 1] - off;
  const int m0 = m_idx * BM;
  if (m0 >= cnt) return;
  const int n0 = n_idx * BN;
  const int pe0 = poff[e];
  const int pcnt = poff[e + 1] - pe0;
  const int pm0 = pe0 + m0;
  const int rt0 = pm0 >> 7;
  const int rt1 = (m0 + 128 < pcnt) ? rt0 + 1 : rt0;  // clamp: pad rows' outputs are discarded

  __shared__ unsigned short sA[2][BM * BK];  // [256][64] linear
  __shared__ unsigned short sB[2][BN * BK];

  const int tid = threadIdx.x;
  const int lane = tid & 63;
  const int w = tid >> 6;          // 0..7
  const int wm = w >> 2;           // 0..1 (128 rows each)
  const int wn = w & 3;            // 0..3 (64 cols each)
  const int fr = lane & 15;
  const int koff = (lane >> 4) * 8;

  const unsigned short* aB0;
  const unsigned short* aB1;
  const unsigned short* bB;
  if constexpr (UP) {
    aB0 = A + (size_t)(rt0 * 16) * 8192;                     // kt tiles 0..15
    aB1 = A + (size_t)(rt1 * 16) * 8192;
    bB = Bw + (size_t)((e * 16 + n_idx) * 16) * 16384;
  } else {
    aB0 = A + (size_t)(rt0 * 64 + ks * 16) * 8192;           // 64 kt tiles, chunk ks
    aB1 = A + (size_t)(rt1 * 64 + ks * 16) * 8192;
    bB = Bw + (size_t)((e * 4 + n_idx) * 64 + ks * 16) * 16384;
  }
  const unsigned short* aSrcW = (w < 4 ? aB0 : aB1) + (w & 3) * 2048 + lane * 8;
  const unsigned short* bSrcW = bB + w * 2048 + lane * 8;

  floatx4 acc[8][4];
  const floatx4 zero = {0.f, 0.f, 0.f, 0.f};
#pragma unroll
  for (int i = 0; i < 8; ++i)
#pragma unroll
    for (int j = 0; j < 4; ++j) acc[i][j] = zero;

  STAGE(0, 0)
  __syncthreads();

  int cur = 0;
  for (int s = 0; s < NSTEP; ++s) {
    if (s + 1 < NSTEP) STAGE(cur ^ 1, s + 1)  // async prefetch next K-step

#pragma unroll
    for (int kk = 0; kk < 2; ++kk) {
      short8 a[8], bq[4];
#pragma unroll
      for (int i = 0; i < 8; ++i)
        a[i] = *(const short8*)(&sA[cur][(wm * 128 + i * 16 + fr) * 64 + kk * 32 + koff]);
#pragma unroll
      for (int j = 0; j < 4; ++j)
        bq[j] = *(const short8*)(&sB[cur][(wn * 64 + j * 16 + fr) * 64 + kk * 32 + koff]);
#pragma unroll
      for (int i = 0; i < 8; ++i)
#pragma unroll
        for (int j = 0; j < 4; ++j)
          acc[i][j] = __builtin_amdgcn_mfma_f32_16x16x32_bf16(a[i], bq[j], acc[i][j], 0, 0, 0);
    }

    __syncthreads();  // drains vmcnt (staged loads) + all reads of sX[cur] done
    cur ^= 1;
  }

  // epilogue: C/D layout col=lane&15, row=(lane>>4)*4+jj
  const int rsub = (lane >> 4) * 4;
#pragma unroll
  for (int i = 0; i < 8; ++i) {
#pragma unroll
    for (int j = 0; j < 4; ++j) {
#pragma unroll
      for (int jj = 0; jj < 4; ++jj) {
        const int r = wm * 128 + i * 16 + rsub + jj;
        const int c = wn * 64 + j * 16 + fr;
        if (m0 + r < cnt) {
          if constexpr (UP) {
            const int pr = pm0 + r;
            const int gc = n0 + c;
            Hout[((size_t)(pr >> 7) * 64 + (gc >> 6)) * 8192 + (pr & 127) * 64 + (gc & 63)] =
                f2b(acc[i][j][jj]);
          } else {
            const int t = token_list[off + m0 + r];
            atomicAdd(&Out[(size_t)t * MODEL_DIM + n0 + c], acc[i][j][jj]);
          }
        }
      }
    }
  }
}

extern "C" void kernel_launch(void* const* d_in, const int* in_sizes, int n_in,
                              void* d_out, int out_size, void* d_ws, size_t ws_size,
                              hipStream_t stream) {
  const float* x = (const float*)d_in[0];
  const float* gw = (const float*)d_in[1];
  const float* w_up = (const float*)d_in[2];
  const float* w_down = (const float*)d_in[3];
  float* out = (float*)d_out;

  const int T = in_sizes[0] / MODEL_DIM;  // 2048
  const int total = 2 * T;                // 4096 routed rows

  char* wsb = (char*)d_ws;
  int* eids = (int*)wsb;            // [total]
  int* counts = eids + total;       // [8]
  int* offsets = counts + 8;        // [9]
  int* cursor = offsets + 12;       // [8]
  int* poff = cursor + 8;           // [9]
  int* token_list = poff + 12;      // [total]
  unsigned short* xg = (unsigned short*)(wsb + (1 << 20));   // 10 MB: 5120 rows, [rt][16][128][64]
  unsigned short* h  = (unsigned short*)(wsb + (11 << 20));  // 40 MB: [rt][64][128][64]
  unsigned short* wT = (unsigned short*)(wsb + (51 << 20));  // 64 MB shared up/down

  hipMemsetAsync(counts, 0, NUM_EXPERTS * sizeof(int), stream);
  hipMemsetAsync(d_out, 0, (size_t)out_size * sizeof(float), stream);

  router_kernel<<<T, 64, 0, stream>>>(x, gw, eids, T);
  hist_kernel<<<(total + 255) / 256, 256, 0, stream>>>(eids, counts, total);
  offsets_kernel<<<1, 64, 0, stream>>>(counts, offsets, cursor, poff);
  scatter_kernel<<<(total + 255) / 256, 256, 0, stream>>>(eids, cursor, token_list, T);
  gather_tile_kernel<<<640, 256, 0, stream>>>(x, offsets, poff, token_list, xg);

  // up: W_up [8][1024][4096] -> [256n][64k] tiles, then GEMM
  wconv_kernel<<<dim3(INTER_DIM / 64, MODEL_DIM / 64, NUM_EXPERTS), 256, 0, stream>>>(
      w_up, wT, MODEL_DIM, INTER_DIM);
  moe_gemm<true><<<dim3(NUM_EXPERTS * 8 * 16), 512, 0, stream>>>(
      xg, wT, h, nullptr, offsets, poff, token_list);

  // down: W_down [8][4096][1024] -> tiles, then GEMM (split-K=4)
  wconv_kernel<<<dim3(MODEL_DIM / 64, INTER_DIM / 64, NUM_EXPERTS), 256, 0, stream>>>(
      w_down, wT, INTER_DIM, MODEL_DIM);
  moe_gemm<false><<<dim3(NUM_EXPERTS * 4 * 8 * 4), 512, 0, stream>>>(
      h, wT, nullptr, out, offsets, poff, token_list);
}

// Round 9
// 308.464 us; speedup vs baseline: 1.3413x; 1.3413x over previous
//
#include <hip/hip_runtime.h>
#include <hip/hip_bf16.h>

#define NUM_EXPERTS 8
#define MODEL_DIM 1024
#define INTER_DIM 4096
#define BM 256
#define BN 256
#define BK 64
// All packed tiles are [rows][64 k] bf16 with 16B-chunk XOR swizzle:
//   phys_chunk = logical_chunk ^ (row & 7)   (chunk = 8 bf16 = 16 B)
// Baked into DRAM layout by pack kernels -> global_load_lds stays linear,
// ds_read applies the XOR. Kills the 16-way bank conflict of row-major 128B rows.

typedef __attribute__((ext_vector_type(8))) short short8;
typedef __attribute__((ext_vector_type(8))) unsigned short ushort8;
typedef __attribute__((ext_vector_type(4))) unsigned short ushort4v;
typedef __attribute__((ext_vector_type(4))) float floatx4;

__device__ __forceinline__ unsigned short f2b(float f) {
  union { float f; unsigned int u; } v; v.f = f;
  unsigned int r = v.u + 0x7fffu + ((v.u >> 16) & 1u);
  return (unsigned short)(r >> 16);
}

#define GLOAD16(g, l)                                                                   \
  __builtin_amdgcn_global_load_lds((const __attribute__((address_space(1))) unsigned int*)(g), \
                                   (__attribute__((address_space(3))) unsigned int*)(l), 16, 0, 0)

// ---------------- router ----------------
__global__ __launch_bounds__(64) void router_kernel(const float* __restrict__ x,
                                                    const float* __restrict__ gw,
                                                    int* __restrict__ eids, int T) {
  int t = blockIdx.x;
  int lane = threadIdx.x;
  float acc[NUM_EXPERTS];
#pragma unroll
  for (int e = 0; e < NUM_EXPERTS; ++e) acc[e] = 0.f;
  const float* xr = x + (size_t)t * MODEL_DIM;
#pragma unroll 4
  for (int i = lane; i < MODEL_DIM; i += 64) {
    float xv = xr[i];
#pragma unroll
    for (int e = 0; e < NUM_EXPERTS; ++e) acc[e] += xv * gw[e * MODEL_DIM + i];
  }
#pragma unroll
  for (int e = 0; e < NUM_EXPERTS; ++e) {
    float v = acc[e];
#pragma unroll
    for (int off = 32; off > 0; off >>= 1) v += __shfl_xor(v, off);
    acc[e] = v;
  }
  if (lane == 0) {
    int e0 = 0; float b0 = acc[0];
#pragma unroll
    for (int e = 1; e < NUM_EXPERTS; ++e) if (acc[e] > b0) { b0 = acc[e]; e0 = e; }
    int e1 = -1; float b1 = -3.4e38f;
#pragma unroll
    for (int e = 0; e < NUM_EXPERTS; ++e) if (e != e0 && acc[e] > b1) { b1 = acc[e]; e1 = e; }
    eids[t] = e0;
    eids[T + t] = e1;
  }
}

__global__ void hist_kernel(const int* __restrict__ eids, int* __restrict__ counts, int total) {
  int i = blockIdx.x * blockDim.x + threadIdx.x;
  if (i < total) atomicAdd(&counts[eids[i]], 1);
}

__global__ void offsets_kernel(const int* __restrict__ counts, int* __restrict__ offsets,
                               int* __restrict__ cursor, int* __restrict__ poff) {
  if (threadIdx.x == 0 && blockIdx.x == 0) {
    int s = 0, ps = 0;
    for (int e = 0; e < NUM_EXPERTS; ++e) {
      offsets[e] = s; cursor[e] = s; poff[e] = ps;
      s += counts[e];
      ps += ((counts[e] + 127) >> 7) << 7;
    }
    offsets[NUM_EXPERTS] = s;
    poff[NUM_EXPERTS] = ps;
  }
}

__global__ void scatter_kernel(const int* __restrict__ eids, int* __restrict__ cursor,
                               int* __restrict__ token_list, int* __restrict__ tok2row, int T) {
  int i = blockIdx.x * blockDim.x + threadIdx.x;
  if (i < 2 * T) {
    int e = eids[i];
    int pos = atomicAdd(&cursor[e], 1);
    int t = (i >= T) ? (i - T) : i;
    token_list[pos] = t;
    tok2row[t * 2 + (i >= T ? 1 : 0)] = pos;  // each token's 2 routed rows
  }
}

// ---------------- gather + fp32->bf16 + swizzled half-tile pack ----------
// xg: [p/128][kt(16)][128][64] with chunk XOR (row&7). Zero pads.
__global__ __launch_bounds__(256) void gather_tile_kernel(
    const float* __restrict__ X, const int* __restrict__ offsets,
    const int* __restrict__ poff, const int* __restrict__ token_list,
    unsigned short* __restrict__ xg) {
  const int tid = threadIdx.x;
  const int p = blockIdx.x * 8 + (tid >> 5);
  const int kb = tid & 31;
  if (p >= poff[NUM_EXPERTS]) return;
  int e = 0;
#pragma unroll
  for (int q = 1; q < NUM_EXPERTS; ++q) if (p >= poff[q]) e = q;
  const int local = p - poff[e];
  const int cnt = offsets[e + 1] - offsets[e];
  const int row = p & 127;
  const int r7 = row & 7;
  unsigned short* dst =
      xg + ((size_t)(p >> 7) * 16 + (kb >> 1)) * 8192 + row * 64;
  const int lc0 = (kb & 1) * 4;  // logical chunk base within row
  if (local < cnt) {
    const int tok = token_list[offsets[e] + local];
    const float* src = X + (size_t)tok * MODEL_DIM + kb * 32;
#pragma unroll
    for (int cc = 0; cc < 4; ++cc) {
      float4 v0 = *(const float4*)(src + cc * 8);
      float4 v1 = *(const float4*)(src + cc * 8 + 4);
      ushort8 s;
      s[0] = f2b(v0.x); s[1] = f2b(v0.y); s[2] = f2b(v0.z); s[3] = f2b(v0.w);
      s[4] = f2b(v1.x); s[5] = f2b(v1.y); s[6] = f2b(v1.z); s[7] = f2b(v1.w);
      *(ushort8*)(dst + (((lc0 + cc) ^ r7) << 3)) = s;
    }
  } else {
    const ushort8 z = {0, 0, 0, 0, 0, 0, 0, 0};
#pragma unroll
    for (int cc = 0; cc < 4; ++cc) *(ushort8*)(dst + (((lc0 + cc) ^ r7) << 3)) = z;
  }
}

// ---------------- W [E][K][N] fp32 -> swizzled [256 n][64 k] bf16 tiles ----------
__global__ __launch_bounds__(256) void wconv_kernel(const float* __restrict__ W,
                                                    unsigned short* __restrict__ O,
                                                    int K, int N) {
  __shared__ unsigned short tile[64 * 68];
  const int e = blockIdx.z;
  const int n0 = blockIdx.x * 64;
  const int k0 = blockIdx.y * 64;
  const int NT = N >> 8, KT = K >> 6;
  const float* src = W + (size_t)e * K * N;
  const int tid = threadIdx.x;
  {
    const int kr = tid >> 2;
    const int nq = (tid & 3) * 16;
    const float* p = src + (size_t)(k0 + kr) * N + n0 + nq;
#pragma unroll
    for (int j = 0; j < 4; ++j) {
      float4 v = *(const float4*)(p + j * 4);
      ushort4v s;
      s[0] = f2b(v.x); s[1] = f2b(v.y); s[2] = f2b(v.z); s[3] = f2b(v.w);
      *(ushort4v*)(&tile[kr * 68 + nq + j * 4]) = s;
    }
  }
  __syncthreads();
  {
    const int nl = tid >> 2;
    const int n = n0 + nl;
    const int r7 = n & 7;
    const int ks = (tid & 3) * 16;
#pragma unroll
    for (int c = 0; c < 4; ++c) {
      const int tk = k0 + ks + c * 4;
      const int ktl = tk & 63;
      ushort4v s;
      s[0] = tile[(ks + c * 4 + 0) * 68 + nl];
      s[1] = tile[(ks + c * 4 + 1) * 68 + nl];
      s[2] = tile[(ks + c * 4 + 2) * 68 + nl];
      s[3] = tile[(ks + c * 4 + 3) * 68 + nl];
      unsigned short* q = O + ((size_t)(e * NT + (n >> 8)) * KT + (tk >> 6)) * 16384 +
                          (n & 255) * 64 + ((((ktl >> 3) ^ r7)) << 3) + (ktl & 7);
      *(ushort4v*)q = s;
    }
  }
}

// ---------------- grouped GEMM, 256x256, BK=64, swizzled LDS reads ----------
#define STAGE(CUR, S) {                                                    \
  _Pragma("unroll")                                                        \
  for (int q = 0; q < 4; ++q)                                              \
    GLOAD16(aSrcW + (size_t)(S) * 8192 + q * 512, &sA[CUR][w * 2048 + q * 512]);  \
  _Pragma("unroll")                                                        \
  for (int q = 0; q < 4; ++q)                                              \
    GLOAD16(bSrcW + (size_t)(S) * 16384 + q * 512, &sB[CUR][w * 2048 + q * 512]); \
}

template <bool UP>
__global__ __launch_bounds__(512) void moe_gemm(
    const unsigned short* __restrict__ A,
    const unsigned short* __restrict__ Bw,
    unsigned short* __restrict__ Hout,
    float* __restrict__ Out,
    float* __restrict__ Pout,
    const int* __restrict__ offsets,
    const int* __restrict__ poff,
    const int* __restrict__ token_list,
    int usePartial) {
  constexpr int NSTEP = 16;

  const int b = blockIdx.x;
  const int e = b & 7;
  const int rem = b >> 3;
  int m_idx, n_idx, ks;
  if constexpr (UP) {
    m_idx = rem & 7;
    n_idx = rem >> 3;
    ks = 0;
  } else {
    n_idx = rem & 3;
    m_idx = (rem >> 2) & 7;
    ks = rem >> 5;
  }

  const int off = offsets[e];
  const int cnt = offsets[e + 1] - off;
  const int m0 = m_idx * BM;
  if (m0 >= cnt) return;
  const int n0 = n_idx * BN;
  const int pe0 = poff[e];
  const int pcnt = poff[e + 1] - pe0;
  const int pm0 = pe0 + m0;
  const int rt0 = pm0 >> 7;
  const int rt1 = (m0 + 128 < pcnt) ? rt0 + 1 : rt0;

  __shared__ unsigned short sA[2][BM * BK];
  __shared__ unsigned short sB[2][BN * BK];

  const int tid = threadIdx.x;
  const int lane = tid & 63;
  const int w = tid >> 6;
  const int wm = w >> 2;
  const int wn = w & 3;
  const int fr = lane & 15;
  const int fr7 = fr & 7;
  const int csel = lane >> 4;

  const unsigned short* aB0;
  const unsigned short* aB1;
  const unsigned short* bB;
  if constexpr (UP) {
    aB0 = A + (size_t)(rt0 * 16) * 8192;
    aB1 = A + (size_t)(rt1 * 16) * 8192;
    bB = Bw + (size_t)((e * 16 + n_idx) * 16) * 16384;
  } else {
    aB0 = A + (size_t)(rt0 * 64 + ks * 16) * 8192;
    aB1 = A + (size_t)(rt1 * 64 + ks * 16) * 8192;
    bB = Bw + (size_t)((e * 4 + n_idx) * 64 + ks * 16) * 16384;
  }
  const unsigned short* aSrcW = (w < 4 ? aB0 : aB1) + (w & 3) * 2048 + lane * 8;
  const unsigned short* bSrcW = bB + w * 2048 + lane * 8;

  floatx4 acc[8][4];
  const floatx4 zero = {0.f, 0.f, 0.f, 0.f};
#pragma unroll
  for (int i = 0; i < 8; ++i)
#pragma unroll
    for (int j = 0; j < 4; ++j) acc[i][j] = zero;

  STAGE(0, 0)
  __syncthreads();

  int cur = 0;
  for (int s = 0; s < NSTEP; ++s) {
    if (s + 1 < NSTEP) STAGE(cur ^ 1, s + 1)

#pragma unroll
    for (int kk = 0; kk < 2; ++kk) {
      // swizzled chunk offset: logical chunk (kk*4 + csel) XOR row&7 (= fr&7)
      const int cofs = (((kk << 2) + csel) ^ fr7) << 3;
      short8 a[8], bq[4];
#pragma unroll
      for (int i = 0; i < 8; ++i)
        a[i] = *(const short8*)(&sA[cur][(wm * 128 + i * 16 + fr) * 64 + cofs]);
#pragma unroll
      for (int j = 0; j < 4; ++j)
        bq[j] = *(const short8*)(&sB[cur][(wn * 64 + j * 16 + fr) * 64 + cofs]);
#pragma unroll
      for (int i = 0; i < 8; ++i)
#pragma unroll
        for (int j = 0; j < 4; ++j)
          acc[i][j] = __builtin_amdgcn_mfma_f32_16x16x32_bf16(a[i], bq[j], acc[i][j], 0, 0, 0);
    }

    __syncthreads();
    cur ^= 1;
  }

  // epilogue: C/D col=lane&15, row=(lane>>4)*4+jj
  const int rsub = (lane >> 4) * 4;
#pragma unroll
  for (int i = 0; i < 8; ++i) {
#pragma unroll
    for (int j = 0; j < 4; ++j) {
#pragma unroll
      for (int jj = 0; jj < 4; ++jj) {
        const int r = wm * 128 + i * 16 + rsub + jj;
        const int c = wn * 64 + j * 16 + fr;
        if (m0 + r < cnt) {
          if constexpr (UP) {
            const int pr = pm0 + r;
            const int gc = n0 + c;
            const int row = pr & 127;
            const int kt = gc & 63;
            Hout[((size_t)(pr >> 7) * 64 + (gc >> 6)) * 8192 + row * 64 +
                 ((((kt >> 3) ^ (row & 7))) << 3) + (kt & 7)] = f2b(acc[i][j][jj]);
          } else {
            if (usePartial) {
              Pout[((size_t)ks * 4096 + (off + m0 + r)) * 1024 + n0 + c] = acc[i][j][jj];
            } else {
              const int t = token_list[off + m0 + r];
              atomicAdd(&Out[(size_t)t * MODEL_DIM + n0 + c], acc[i][j][jj]);
            }
          }
        }
      }
    }
  }
}

// ---------------- combine: out[t] = sum over 2 routed rows x 4 splits ----------
__global__ __launch_bounds__(256) void combine_kernel(const float* __restrict__ P,
                                                      const int* __restrict__ tok2row,
                                                      float* __restrict__ out) {
  const int t = blockIdx.x;
  const int c = threadIdx.x;  // float4 index, 256*4 = 1024
  const int r0 = tok2row[2 * t];
  const int r1 = tok2row[2 * t + 1];
  float4 s = {0.f, 0.f, 0.f, 0.f};
#pragma unroll
  for (int sp = 0; sp < 4; ++sp) {
    float4 a = ((const float4*)(P + ((size_t)sp * 4096 + r0) * 1024))[c];
    float4 bv = ((const float4*)(P + ((size_t)sp * 4096 + r1) * 1024))[c];
    s.x += a.x + bv.x; s.y += a.y + bv.y; s.z += a.z + bv.z; s.w += a.w + bv.w;
  }
  ((float4*)(out + (size_t)t * MODEL_DIM))[c] = s;
}

extern "C" void kernel_launch(void* const* d_in, const int* in_sizes, int n_in,
                              void* d_out, int out_size, void* d_ws, size_t ws_size,
                              hipStream_t stream) {
  const float* x = (const float*)d_in[0];
  const float* gw = (const float*)d_in[1];
  const float* w_up = (const float*)d_in[2];
  const float* w_down = (const float*)d_in[3];
  float* out = (float*)d_out;

  const int T = in_sizes[0] / MODEL_DIM;  // 2048
  const int total = 2 * T;                // 4096

  char* wsb = (char*)d_ws;
  int* eids = (int*)wsb;
  int* counts = eids + total;
  int* offsets = counts + 8;
  int* cursor = offsets + 12;
  int* poff = cursor + 8;
  int* token_list = poff + 12;
  int* tok2row = token_list + total;
  unsigned short* xg = (unsigned short*)(wsb + (1ULL << 20));    // 10 MiB
  unsigned short* h  = (unsigned short*)(wsb + (11ULL << 20));   // 40 MiB
  unsigned short* wT = (unsigned short*)(wsb + (51ULL << 20));   // 64 MiB
  float* P = (float*)(wsb + (115ULL << 20));                     // 64 MiB (optional)
  const int usePartial = (ws_size >= (180ULL << 20)) ? 1 : 0;

  hipMemsetAsync(counts, 0, NUM_EXPERTS * sizeof(int), stream);
  if (!usePartial) hipMemsetAsync(d_out, 0, (size_t)out_size * sizeof(float), stream);

  router_kernel<<<T, 64, 0, stream>>>(x, gw, eids, T);
  hist_kernel<<<(total + 255) / 256, 256, 0, stream>>>(eids, counts, total);
  offsets_kernel<<<1, 64, 0, stream>>>(counts, offsets, cursor, poff);
  scatter_kernel<<<(total + 255) / 256, 256, 0, stream>>>(eids, cursor, token_list, tok2row, T);
  gather_tile_kernel<<<640, 256, 0, stream>>>(x, offsets, poff, token_list, xg);

  wconv_kernel<<<dim3(INTER_DIM / 64, MODEL_DIM / 64, NUM_EXPERTS), 256, 0, stream>>>(
      w_up, wT, MODEL_DIM, INTER_DIM);
  moe_gemm<true><<<dim3(NUM_EXPERTS * 8 * 16), 512, 0, stream>>>(
      xg, wT, h, nullptr, nullptr, offsets, poff, token_list, 0);

  wconv_kernel<<<dim3(MODEL_DIM / 64, INTER_DIM / 64, NUM_EXPERTS), 256, 0, stream>>>(
      w_down, wT, INTER_DIM, MODEL_DIM);
  moe_gemm<false><<<dim3(NUM_EXPERTS * 4 * 8 * 4), 512, 0, stream>>>(
      h, wT, nullptr, out, P, offsets, poff, token_list, usePartial);
  if (usePartial) combine_kernel<<<T, 256, 0, stream>>>(P, tok2row, out);
}